// Round 5
// baseline (179.587 us; speedup 1.0000x reference)
//
#include <hip/hip_runtime.h>

#define CCH 256
#define HH 200
#define WW 200
#define HWW (HH * WW)
#define PHB 7
#define PWB 7
#define NBINS 49
#define OUTSZ (CCH * NBINS)   // 12544 floats per roi

typedef float f4v __attribute__((ext_vector_type(4)));
typedef unsigned short us4 __attribute__((ext_vector_type(4)));
typedef unsigned u2v __attribute__((ext_vector_type(2)));
typedef unsigned u4v __attribute__((ext_vector_type(4)));

__device__ __forceinline__ unsigned short f2bf(float f) {
  unsigned u = __builtin_bit_cast(unsigned, f);
  u += 0x7fffu + ((u >> 16) & 1u);   // round-to-nearest-even
  return (unsigned short)(u >> 16);
}
__device__ __forceinline__ float bf_lo(unsigned u) {
  return __builtin_bit_cast(float, u << 16);
}
__device__ __forceinline__ float bf_hi(unsigned u) {
  return __builtin_bit_cast(float, u & 0xffff0000u);
}

// ---------------------------------------------------------------------------
// Transpose+cast (B, C, H*W) fp32 -> (B, H*W, C) bf16.  (unchanged — near its
// 123 MB / 6.3 TB/s floor)
// ---------------------------------------------------------------------------
__global__ __launch_bounds__(256) void transpose_kernel(
    const float* __restrict__ in, unsigned short* __restrict__ out) {
  __shared__ float tile[64][65];
  const int b  = blockIdx.z;
  const int p0 = blockIdx.x * 64;   // pixel tile (HWW = 40000 = 625*64)
  const int c0 = blockIdx.y * 64;   // channel tile
  const int t  = threadIdx.x;
  const int k  = t & 15;
  const int r0 = t >> 4;
  const float* ip = in  + (size_t)b * CCH * HWW;
  unsigned short* op = out + (size_t)b * HWW * CCH;
#pragma unroll
  for (int rr = 0; rr < 4; ++rr) {
    const int c = r0 + rr * 16;
    const f4v v = __builtin_nontemporal_load(
        (const f4v*)(ip + (size_t)(c0 + c) * HWW + p0 + 4 * k));
    tile[c][4 * k + 0] = v.x;
    tile[c][4 * k + 1] = v.y;
    tile[c][4 * k + 2] = v.z;
    tile[c][4 * k + 3] = v.w;
  }
  __syncthreads();
#pragma unroll
  for (int rr = 0; rr < 4; ++rr) {
    const int p = r0 + rr * 16;
    us4 v;
    v.x = f2bf(tile[4 * k + 0][p]);
    v.y = f2bf(tile[4 * k + 1][p]);
    v.z = f2bf(tile[4 * k + 2][p]);
    v.w = f2bf(tile[4 * k + 3][p]);
    *(us4*)(op + (size_t)(p0 + p) * CCH + c0 + 4 * k) = v;
  }
}

// ---------------------------------------------------------------------------
// Spatial sort of rois (round 11). One 1024-thread block, bitonic sort in
// LDS on key = (batch<<10) | morton5x5(cy/8, cx/8). Output: permutation
// perm[sorted_pos] = original roi index. Any outcome of the pair-exchange
// sort is a PERMUTATION -> correctness cannot depend on sort quality; a
// comparator bug is a perf no-op, not a wrong answer. N>1024 -> identity.
// ---------------------------------------------------------------------------
__global__ __launch_bounds__(1024) void sort_kernel(
    const float* __restrict__ rois, const int* __restrict__ sidx,
    const int n, int* __restrict__ perm) {
  const int t = threadIdx.x;
  if (n > 1024) {                  // fallback: identity permutation
    for (int i = t; i < n; i += 1024) perm[i] = i;
    return;
  }
  __shared__ unsigned s_key[1024];
  __shared__ int      s_idx[1024];
  unsigned key = 0xFFFFFFFFu;      // pads sort to the end (never dispatched)
  if (t < n) {
    const float cx = 0.5f * (rois[4 * t + 0] + rois[4 * t + 2]);
    const float cy = 0.5f * (rois[4 * t + 1] + rois[4 * t + 3]);
    int qx = (int)(cx * 0.125f); qx = qx < 0 ? 0 : (qx > 31 ? 31 : qx);
    int qy = (int)(cy * 0.125f); qy = qy < 0 ? 0 : (qy > 31 ? 31 : qy);
    unsigned m = 0;
#pragma unroll
    for (int i = 0; i < 5; ++i)
      m |= (((unsigned)(qy >> i) & 1u) << (2 * i + 1)) |
           (((unsigned)(qx >> i) & 1u) << (2 * i));
    key = ((unsigned)sidx[t] << 10) | m;
  }
  s_key[t] = key;
  s_idx[t] = t;
  __syncthreads();
  for (int k = 2; k <= 1024; k <<= 1) {
    for (int j = k >> 1; j > 0; j >>= 1) {
      const int p = t ^ j;
      if (p > t) {
        const unsigned a = s_key[t], b = s_key[p];
        const bool up = ((t & k) == 0);
        if (up ? (a > b) : (a < b)) {
          s_key[t] = b; s_key[p] = a;
          const int ti = s_idx[t]; s_idx[t] = s_idx[p]; s_idx[p] = ti;
        }
      }
      __syncthreads();
    }
  }
  if (t < n) perm[t] = s_idx[t];
}

// ---------------------------------------------------------------------------
// RoI Align on bf16 NHWC. Grid = 4*N: block = (roi, channel-quarter).
//
// Round 11. R10 post-mortem: 32-wave occupancy + coalesced flush landed but
// roi stayed ~45us -> bound by L2-MISS SERVICE of the gather (~3 TB/s on
// FETCH=139MB, 3.4x the 41MB slab — cross-block re-fetch of shared lines).
// This round attacks the traffic:
//  * rois processed in SPATIALLY SORTED order via perm[] (sort_kernel);
//  * bijective chunked XCD swizzle (m204): each XCD runs a contiguous band
//    of sorted quarter-blocks -> the ~64 rois concurrently resident per XCD
//    are spatial neighbors sharing tap lines in that XCD's L2.
// Compute structure identical to R10 (verified): 64ch/block, bin-quads,
// tap table, LDS 18.8KB -> 8 blocks/CU, unroll 1 to hold VGPR<=64.
// Output written to ORIGINAL roi slot -> sort affects schedule only.
// ---------------------------------------------------------------------------
struct __align__(16) Tap {
  unsigned off[4];   // byte offsets of taps (y0,x0),(y0,x1),(y1,x0),(y1,x1)
  float    w[4];     // matching weights, premultiplied by 0.25*valid
};

__global__ __launch_bounds__(256) void roi_kernel(
    const unsigned short* __restrict__ feat, const float* __restrict__ rois,
    const int* __restrict__ sidx, const int* __restrict__ perm,
    float* __restrict__ out) {
  __shared__ float s_out[64 * NBINS];   // [c_local][bin], 12544 B
  __shared__ Tap   s_tab[196];          // 6272 B

  // Bijective chunked XCD swizzle (m204): XCD x gets sorted-contiguous
  // quarter-blocks [chunk_start(x), ...). Bijection holds for any gridDim.
  const unsigned nwg  = gridDim.x;
  const unsigned orig = blockIdx.x;
  const unsigned q8   = nwg >> 3, r8 = nwg & 7;
  const unsigned xcd  = orig & 7, ii = orig >> 3;
  const unsigned j    =
      (xcd < r8 ? xcd * (q8 + 1) : r8 * (q8 + 1) + (xcd - r8) * q8) + ii;

  const int n  = perm[j >> 2];          // sorted -> original roi index
  const int hq = j & 3;                 // channel quarter: [64*hq, 64*hq+64)
  const int t  = threadIdx.x;
  const int bb = sidx[n];

  if (t < 196) {
    const float x1 = rois[n * 4 + 0];
    const float y1 = rois[n * 4 + 1];
    const float x2 = rois[n * 4 + 2];
    const float y2 = rois[n * 4 + 3];
    const float bin_w = fmaxf(x2 - x1, 1.0f) * (1.0f / 7.0f);
    const float bin_h = fmaxf(y2 - y1, 1.0f) * (1.0f / 7.0f);
    const int iy = t / 14;               // sample row 0..13
    const int ix = t - iy * 14;          // sample col 0..13
    const float ys = y1 + ((float)iy + 0.5f) * 0.5f * bin_h;
    const float xs = x1 + ((float)ix + 0.5f) * 0.5f * bin_w;
    const float vy = (ys >= -1.0f && ys <= (float)HH) ? 1.0f : 0.0f;
    const float vx = (xs >= -1.0f && xs <= (float)WW) ? 1.0f : 0.0f;
    const float yc = fminf(fmaxf(ys, 0.0f), (float)(HH - 1));
    const float xc = fminf(fmaxf(xs, 0.0f), (float)(WW - 1));
    const int yy0 = (int)yc;
    const int xx0 = (int)xc;
    const int yy1 = min(yy0 + 1, HH - 1);
    const int xx1 = min(xx0 + 1, WW - 1);
    const float ly = yc - (float)yy0, hy = 1.0f - ly;
    const float lx = xc - (float)xx0, hx = 1.0f - lx;
    const float f = vy * vx * 0.25f;     // fold 2x2-sample mean + mask into w
    const unsigned r0 = (unsigned)(yy0 * WW);
    const unsigned r1 = (unsigned)(yy1 * WW);
    s_tab[t].off[0] = (r0 + (unsigned)xx0) * (CCH * 2);  // NHWC byte offsets
    s_tab[t].off[1] = (r0 + (unsigned)xx1) * (CCH * 2);
    s_tab[t].off[2] = (r1 + (unsigned)xx0) * (CCH * 2);
    s_tab[t].off[3] = (r1 + (unsigned)xx1) * (CCH * 2);
    s_tab[t].w[0] = f * hy * hx;
    s_tab[t].w[1] = f * hy * lx;
    s_tab[t].w[2] = f * ly * hx;
    s_tab[t].w[3] = f * ly * lx;
  }
  __syncthreads();

  const int lane = t & 63;
  const int wv   = t >> 6;                                // wave id 0..3
  const int lq   = lane >> 4;                             // bin within quad
  const unsigned laneoff = (unsigned)((lane & 15) << 3);  // 8 B = 4 of 64 ch
  const char* __restrict__ base =
      (const char*)feat + ((size_t)bb * HWW * CCH + 64 * hq) * 2;

  // 13 bin-quads strided over 4 waves (quad 12 = bin 48 + 3 masked dummies).
#pragma unroll 1
  for (int p = wv; p < 13; p += 4) {
    const int mybin = 4 * p + lq;
    const int bin   = min(mybin, NBINS - 1);   // clamp for the dummy tail
    const int ph  = bin / PWB;
    const int pw  = bin - ph * PWB;
    const int s00 = (2 * ph) * 14 + 2 * pw;
    float a0 = 0.0f, a1 = 0.0f, a2 = 0.0f, a3 = 0.0f;
#pragma unroll
    for (int sy = 0; sy < 2; ++sy) {
#pragma unroll
      for (int sx = 0; sx < 2; ++sx) {
        const Tap* tp = &s_tab[s00 + sy * 14 + sx];
        const u4v o4 = *(const u4v*)tp->off;
        const f4v w4 = *(const f4v*)tp->w;
        const u2v q00 = *(const u2v*)(base + (o4.x + laneoff));
        const u2v q01 = *(const u2v*)(base + (o4.y + laneoff));
        const u2v q10 = *(const u2v*)(base + (o4.z + laneoff));
        const u2v q11 = *(const u2v*)(base + (o4.w + laneoff));
        a0 += w4.x * bf_lo(q00.x) + w4.y * bf_lo(q01.x)
            + w4.z * bf_lo(q10.x) + w4.w * bf_lo(q11.x);
        a1 += w4.x * bf_hi(q00.x) + w4.y * bf_hi(q01.x)
            + w4.z * bf_hi(q10.x) + w4.w * bf_hi(q11.x);
        a2 += w4.x * bf_lo(q00.y) + w4.y * bf_lo(q01.y)
            + w4.z * bf_lo(q10.y) + w4.w * bf_lo(q11.y);
        a3 += w4.x * bf_hi(q00.y) + w4.y * bf_hi(q01.y)
            + w4.z * bf_hi(q10.y) + w4.w * bf_hi(q11.y);
      }
    }
    if (mybin < NBINS) {
      const int c0 = (lane & 15) << 2;     // local channel base (0..60)
      s_out[(c0 + 0) * NBINS + mybin] = a0;
      s_out[(c0 + 1) * NBINS + mybin] = a1;
      s_out[(c0 + 2) * NBINS + mybin] = a2;
      s_out[(c0 + 3) * NBINS + mybin] = a3;
    }
  }
  __syncthreads();

  // Quarter slab is contiguous in global: 64*49 floats = 784 float4,
  // written to the ORIGINAL roi slot n.
  const f4v* so4 = (const f4v*)s_out;
  f4v*       on4 = (f4v*)(out + (size_t)n * OUTSZ + hq * (64 * NBINS));
  for (int i = t; i < (64 * NBINS) / 4; i += 256) on4[i] = so4[i];
}

// ---------------------------------------------------------------------------
// Scalar NCHW fp32 fallback (only if ws too small for the bf16 copy).
// ---------------------------------------------------------------------------
__global__ __launch_bounds__(256) void roi_kernel_nchw(
    const float* __restrict__ feat, const float* __restrict__ rois,
    const int* __restrict__ sidx, float* __restrict__ out) {
  __shared__ float s_out[OUTSZ];
  __shared__ int   s_yi[2][14];
  __shared__ int   s_xi[2][14];
  __shared__ float s_ly[14], s_hy[14], s_vy[14];
  __shared__ float s_lx[14], s_hx[14], s_vx[14];
  const int n = blockIdx.x;
  const int t = threadIdx.x;
  const float x1 = rois[n * 4 + 0], y1 = rois[n * 4 + 1];
  const float x2 = rois[n * 4 + 2], y2 = rois[n * 4 + 3];
  const int   bb = sidx[n];
  const float bin_w = fmaxf(x2 - x1, 1.0f) / 7.0f;
  const float bin_h = fmaxf(y2 - y1, 1.0f) / 7.0f;
  if (t < 14) {
    const float tt = ((float)t + 0.5f) * 0.5f;
    const float ys = y1 + tt * bin_h;
    s_vy[t] = (ys >= -1.0f && ys <= (float)HH) ? 1.0f : 0.0f;
    const float yc = fminf(fmaxf(ys, 0.0f), (float)(HH - 1));
    const int yy0 = (int)yc, yy1 = min(yy0 + 1, HH - 1);
    s_yi[0][t] = yy0 * WW; s_yi[1][t] = yy1 * WW;
    s_ly[t] = yc - (float)yy0; s_hy[t] = 1.0f - s_ly[t];
  } else if (t < 28) {
    const int i = t - 14;
    const float tt = ((float)i + 0.5f) * 0.5f;
    const float xs = x1 + tt * bin_w;
    s_vx[i] = (xs >= -1.0f && xs <= (float)WW) ? 1.0f : 0.0f;
    const float xc = fminf(fmaxf(xs, 0.0f), (float)(WW - 1));
    const int xx0 = (int)xc, xx1 = min(xx0 + 1, WW - 1);
    s_xi[0][i] = xx0; s_xi[1][i] = xx1;
    s_lx[i] = xc - (float)xx0; s_hx[i] = 1.0f - s_lx[i];
  }
  __syncthreads();
  const int c = t;
  const float* Fb = feat + ((size_t)bb * CCH + c) * HWW;
  for (int bin = 0; bin < NBINS; ++bin) {
    const int ph = bin / PWB, pw = bin - ph * PWB;
    float acc = 0.0f;
    for (int sy = 0; sy < 2; ++sy) {
      const int iy = ph * 2 + sy;
      for (int sx = 0; sx < 2; ++sx) {
        const int ix = pw * 2 + sx;
        const float m = s_vy[iy] * s_vx[ix];
        acc += m * (s_hy[iy] * (s_hx[ix] * Fb[s_yi[0][iy] + s_xi[0][ix]] +
                                s_lx[ix] * Fb[s_yi[0][iy] + s_xi[1][ix]]) +
                    s_ly[iy] * (s_hx[ix] * Fb[s_yi[1][iy] + s_xi[0][ix]] +
                                s_lx[ix] * Fb[s_yi[1][iy] + s_xi[1][ix]]));
      }
    }
    s_out[c * NBINS + bin] = acc * 0.25f;
  }
  __syncthreads();
  float* on = out + (size_t)n * OUTSZ;
  for (int i = t; i < OUTSZ; i += 256) on[i] = s_out[i];
}

extern "C" void kernel_launch(void* const* d_in, const int* in_sizes, int n_in,
                              void* d_out, int out_size, void* d_ws, size_t ws_size,
                              hipStream_t stream) {
  const float* features = (const float*)d_in[0];
  const float* rois     = (const float*)d_in[1];
  const int*   sidx     = (const int*)d_in[2];
  float*       out      = (float*)d_out;

  const int N = in_sizes[1] / 4;
  const int B = in_sizes[0] / (CCH * HWW);

  const size_t slab = (size_t)B * HWW * CCH * sizeof(unsigned short);
  const size_t need = slab + (size_t)N * sizeof(int);
  if (ws_size >= need) {
    unsigned short* ft   = (unsigned short*)d_ws;
    int*            perm = (int*)((char*)d_ws + slab);
    sort_kernel<<<1, 1024, 0, stream>>>(rois, sidx, N, perm);
    dim3 tgrid(HWW / 64, CCH / 64, B);
    transpose_kernel<<<tgrid, 256, 0, stream>>>(features, ft);
    roi_kernel<<<4 * N, 256, 0, stream>>>(ft, rois, sidx, perm, out);
  } else {
    roi_kernel_nchw<<<N, 256, 0, stream>>>(features, rois, sidx, out);
  }
}

// Round 6
// 171.627 us; speedup vs baseline: 1.0464x; 1.0464x over previous
//
#include <hip/hip_runtime.h>

#define CCH 256
#define HH 200
#define WW 200
#define HWW (HH * WW)
#define PHB 7
#define PWB 7
#define NBINS 49
#define OUTSZ (CCH * NBINS)   // 12544 floats per roi

typedef float f4v __attribute__((ext_vector_type(4)));
typedef unsigned short us4 __attribute__((ext_vector_type(4)));
typedef unsigned u2v __attribute__((ext_vector_type(2)));
typedef unsigned u4v __attribute__((ext_vector_type(4)));

__device__ __forceinline__ unsigned short f2bf(float f) {
  unsigned u = __builtin_bit_cast(unsigned, f);
  u += 0x7fffu + ((u >> 16) & 1u);   // round-to-nearest-even
  return (unsigned short)(u >> 16);
}
__device__ __forceinline__ float bf_lo(unsigned u) {
  return __builtin_bit_cast(float, u << 16);
}
__device__ __forceinline__ float bf_hi(unsigned u) {
  return __builtin_bit_cast(float, u & 0xffff0000u);
}

// ---------------------------------------------------------------------------
// Transpose+cast (B, C, H*W) fp32 -> (B, H*W, C) bf16.  At its streaming
// floor: 164 MB read + 41 MB write ~= 205 MB @ ~6.3 TB/s.
// ---------------------------------------------------------------------------
__global__ __launch_bounds__(256) void transpose_kernel(
    const float* __restrict__ in, unsigned short* __restrict__ out) {
  __shared__ float tile[64][65];
  const int b  = blockIdx.z;
  const int p0 = blockIdx.x * 64;   // pixel tile (HWW = 40000 = 625*64)
  const int c0 = blockIdx.y * 64;   // channel tile
  const int t  = threadIdx.x;
  const int k  = t & 15;
  const int r0 = t >> 4;
  const float* ip = in  + (size_t)b * CCH * HWW;
  unsigned short* op = out + (size_t)b * HWW * CCH;
#pragma unroll
  for (int rr = 0; rr < 4; ++rr) {
    const int c = r0 + rr * 16;
    const f4v v = __builtin_nontemporal_load(
        (const f4v*)(ip + (size_t)(c0 + c) * HWW + p0 + 4 * k));
    tile[c][4 * k + 0] = v.x;
    tile[c][4 * k + 1] = v.y;
    tile[c][4 * k + 2] = v.z;
    tile[c][4 * k + 3] = v.w;
  }
  __syncthreads();
#pragma unroll
  for (int rr = 0; rr < 4; ++rr) {
    const int p = r0 + rr * 16;
    us4 v;
    v.x = f2bf(tile[4 * k + 0][p]);
    v.y = f2bf(tile[4 * k + 1][p]);
    v.z = f2bf(tile[4 * k + 2][p]);
    v.w = f2bf(tile[4 * k + 3][p]);
    *(us4*)(op + (size_t)(p0 + p) * CCH + c0 + 4 * k) = v;
  }
}

// ---------------------------------------------------------------------------
// RoI Align on bf16 NHWC. Grid = 4*N: block = (roi n, channel-quarter hq).
//
// Round 12 = EXACT revert to the round-10 kernel (best verified, 171.7us
// total). Round-11's spatial sort + XCD swizzle regressed (+8us): the serial
// bitonic sort costs ~10us and the locality gain is structurally ~0 —
// in NHWC the reuse granule is one PIXEL (quarter tap line = private 128B
// sub-line), and different rois' bilinear taps coincide on identical integer
// pixels only ~20% of the time even when sorted-adjacent. Cross-roi L2
// sharing is not schedulable. Occupancy exonerated earlier (20->32 waves/CU
// at constant dur). roi_kernel sits at the scattered-gather service floor:
// ~139 MB beyond-L2 traffic @ ~3.1 TB/s ~= 45us.
//
// Structure: 64 ch/block; 196-sample tap table in LDS (6.3 KB); bin-quads
// (16-lane group per bin, lane = 4 ch via dwordx2, 512 B per wave-load);
// coalesced 784-float4 staged flush; LDS 18.8 KB -> 8 blocks/CU;
// #pragma unroll 1 keeps VGPR <= 64 (8 waves/SIMD).
// ---------------------------------------------------------------------------
struct __align__(16) Tap {
  unsigned off[4];   // byte offsets of taps (y0,x0),(y0,x1),(y1,x0),(y1,x1)
  float    w[4];     // matching weights, premultiplied by 0.25*valid
};

__global__ __launch_bounds__(256) void roi_kernel(
    const unsigned short* __restrict__ feat, const float* __restrict__ rois,
    const int* __restrict__ sidx, float* __restrict__ out) {
  __shared__ float s_out[64 * NBINS];   // [c_local][bin], 12544 B
  __shared__ Tap   s_tab[196];          // 6272 B

  const int n  = blockIdx.x >> 2;
  const int hq = blockIdx.x & 3;        // channel quarter: [64*hq, 64*hq+64)
  const int t  = threadIdx.x;
  const int bb = sidx[n];

  if (t < 196) {
    const float x1 = rois[n * 4 + 0];
    const float y1 = rois[n * 4 + 1];
    const float x2 = rois[n * 4 + 2];
    const float y2 = rois[n * 4 + 3];
    const float bin_w = fmaxf(x2 - x1, 1.0f) * (1.0f / 7.0f);
    const float bin_h = fmaxf(y2 - y1, 1.0f) * (1.0f / 7.0f);
    const int iy = t / 14;               // sample row 0..13
    const int ix = t - iy * 14;          // sample col 0..13
    const float ys = y1 + ((float)iy + 0.5f) * 0.5f * bin_h;
    const float xs = x1 + ((float)ix + 0.5f) * 0.5f * bin_w;
    const float vy = (ys >= -1.0f && ys <= (float)HH) ? 1.0f : 0.0f;
    const float vx = (xs >= -1.0f && xs <= (float)WW) ? 1.0f : 0.0f;
    const float yc = fminf(fmaxf(ys, 0.0f), (float)(HH - 1));
    const float xc = fminf(fmaxf(xs, 0.0f), (float)(WW - 1));
    const int yy0 = (int)yc;
    const int xx0 = (int)xc;
    const int yy1 = min(yy0 + 1, HH - 1);
    const int xx1 = min(xx0 + 1, WW - 1);
    const float ly = yc - (float)yy0, hy = 1.0f - ly;
    const float lx = xc - (float)xx0, hx = 1.0f - lx;
    const float f = vy * vx * 0.25f;     // fold 2x2-sample mean + mask into w
    const unsigned r0 = (unsigned)(yy0 * WW);
    const unsigned r1 = (unsigned)(yy1 * WW);
    s_tab[t].off[0] = (r0 + (unsigned)xx0) * (CCH * 2);  // NHWC byte offsets
    s_tab[t].off[1] = (r0 + (unsigned)xx1) * (CCH * 2);
    s_tab[t].off[2] = (r1 + (unsigned)xx0) * (CCH * 2);
    s_tab[t].off[3] = (r1 + (unsigned)xx1) * (CCH * 2);
    s_tab[t].w[0] = f * hy * hx;
    s_tab[t].w[1] = f * hy * lx;
    s_tab[t].w[2] = f * ly * hx;
    s_tab[t].w[3] = f * ly * lx;
  }
  __syncthreads();

  const int lane = t & 63;
  const int wv   = t >> 6;                                // wave id 0..3
  const int lq   = lane >> 4;                             // bin within quad
  const unsigned laneoff = (unsigned)((lane & 15) << 3);  // 8 B = 4 of 64 ch
  const char* __restrict__ base =
      (const char*)feat + ((size_t)bb * HWW * CCH + 64 * hq) * 2;

  // 13 bin-quads strided over 4 waves (quad 12 = bin 48 + 3 masked dummies).
#pragma unroll 1
  for (int p = wv; p < 13; p += 4) {
    const int mybin = 4 * p + lq;
    const int bin   = min(mybin, NBINS - 1);   // clamp for the dummy tail
    const int ph  = bin / PWB;
    const int pw  = bin - ph * PWB;
    const int s00 = (2 * ph) * 14 + 2 * pw;
    float a0 = 0.0f, a1 = 0.0f, a2 = 0.0f, a3 = 0.0f;
#pragma unroll
    for (int sy = 0; sy < 2; ++sy) {
#pragma unroll
      for (int sx = 0; sx < 2; ++sx) {
        const Tap* tp = &s_tab[s00 + sy * 14 + sx];
        const u4v o4 = *(const u4v*)tp->off;
        const f4v w4 = *(const f4v*)tp->w;
        const u2v q00 = *(const u2v*)(base + (o4.x + laneoff));
        const u2v q01 = *(const u2v*)(base + (o4.y + laneoff));
        const u2v q10 = *(const u2v*)(base + (o4.z + laneoff));
        const u2v q11 = *(const u2v*)(base + (o4.w + laneoff));
        a0 += w4.x * bf_lo(q00.x) + w4.y * bf_lo(q01.x)
            + w4.z * bf_lo(q10.x) + w4.w * bf_lo(q11.x);
        a1 += w4.x * bf_hi(q00.x) + w4.y * bf_hi(q01.x)
            + w4.z * bf_hi(q10.x) + w4.w * bf_hi(q11.x);
        a2 += w4.x * bf_lo(q00.y) + w4.y * bf_lo(q01.y)
            + w4.z * bf_lo(q10.y) + w4.w * bf_lo(q11.y);
        a3 += w4.x * bf_hi(q00.y) + w4.y * bf_hi(q01.y)
            + w4.z * bf_hi(q10.y) + w4.w * bf_hi(q11.y);
      }
    }
    if (mybin < NBINS) {
      const int c0 = (lane & 15) << 2;     // local channel base (0..60)
      s_out[(c0 + 0) * NBINS + mybin] = a0;
      s_out[(c0 + 1) * NBINS + mybin] = a1;
      s_out[(c0 + 2) * NBINS + mybin] = a2;
      s_out[(c0 + 3) * NBINS + mybin] = a3;
    }
  }
  __syncthreads();

  // Quarter slab is contiguous in global: 64*49 floats = 784 float4,
  // starting at a 12544-B (16B-aligned) boundary.
  const f4v* so4 = (const f4v*)s_out;
  f4v*       on4 = (f4v*)(out + (size_t)n * OUTSZ + hq * (64 * NBINS));
  for (int i = t; i < (64 * NBINS) / 4; i += 256) on4[i] = so4[i];
}

// ---------------------------------------------------------------------------
// Scalar NCHW fp32 fallback (only if ws too small for the bf16 copy).
// ---------------------------------------------------------------------------
__global__ __launch_bounds__(256) void roi_kernel_nchw(
    const float* __restrict__ feat, const float* __restrict__ rois,
    const int* __restrict__ sidx, float* __restrict__ out) {
  __shared__ float s_out[OUTSZ];
  __shared__ int   s_yi[2][14];
  __shared__ int   s_xi[2][14];
  __shared__ float s_ly[14], s_hy[14], s_vy[14];
  __shared__ float s_lx[14], s_hx[14], s_vx[14];
  const int n = blockIdx.x;
  const int t = threadIdx.x;
  const float x1 = rois[n * 4 + 0], y1 = rois[n * 4 + 1];
  const float x2 = rois[n * 4 + 2], y2 = rois[n * 4 + 3];
  const int   bb = sidx[n];
  const float bin_w = fmaxf(x2 - x1, 1.0f) / 7.0f;
  const float bin_h = fmaxf(y2 - y1, 1.0f) / 7.0f;
  if (t < 14) {
    const float tt = ((float)t + 0.5f) * 0.5f;
    const float ys = y1 + tt * bin_h;
    s_vy[t] = (ys >= -1.0f && ys <= (float)HH) ? 1.0f : 0.0f;
    const float yc = fminf(fmaxf(ys, 0.0f), (float)(HH - 1));
    const int yy0 = (int)yc, yy1 = min(yy0 + 1, HH - 1);
    s_yi[0][t] = yy0 * WW; s_yi[1][t] = yy1 * WW;
    s_ly[t] = yc - (float)yy0; s_hy[t] = 1.0f - s_ly[t];
  } else if (t < 28) {
    const int i = t - 14;
    const float tt = ((float)i + 0.5f) * 0.5f;
    const float xs = x1 + tt * bin_w;
    s_vx[i] = (xs >= -1.0f && xs <= (float)WW) ? 1.0f : 0.0f;
    const float xc = fminf(fmaxf(xs, 0.0f), (float)(WW - 1));
    const int xx0 = (int)xc, xx1 = min(xx0 + 1, WW - 1);
    s_xi[0][i] = xx0; s_xi[1][i] = xx1;
    s_lx[i] = xc - (float)xx0; s_hx[i] = 1.0f - s_lx[i];
  }
  __syncthreads();
  const int c = t;
  const float* Fb = feat + ((size_t)bb * CCH + c) * HWW;
  for (int bin = 0; bin < NBINS; ++bin) {
    const int ph = bin / PWB, pw = bin - ph * PWB;
    float acc = 0.0f;
    for (int sy = 0; sy < 2; ++sy) {
      const int iy = ph * 2 + sy;
      for (int sx = 0; sx < 2; ++sx) {
        const int ix = pw * 2 + sx;
        const float m = s_vy[iy] * s_vx[ix];
        acc += m * (s_hy[iy] * (s_hx[ix] * Fb[s_yi[0][iy] + s_xi[0][ix]] +
                                s_lx[ix] * Fb[s_yi[0][iy] + s_xi[1][ix]]) +
                    s_ly[iy] * (s_hx[ix] * Fb[s_yi[1][iy] + s_xi[0][ix]] +
                                s_lx[ix] * Fb[s_yi[1][iy] + s_xi[1][ix]]));
      }
    }
    s_out[c * NBINS + bin] = acc * 0.25f;
  }
  __syncthreads();
  float* on = out + (size_t)n * OUTSZ;
  for (int i = t; i < OUTSZ; i += 256) on[i] = s_out[i];
}

extern "C" void kernel_launch(void* const* d_in, const int* in_sizes, int n_in,
                              void* d_out, int out_size, void* d_ws, size_t ws_size,
                              hipStream_t stream) {
  const float* features = (const float*)d_in[0];
  const float* rois     = (const float*)d_in[1];
  const int*   sidx     = (const int*)d_in[2];
  float*       out      = (float*)d_out;

  const int N = in_sizes[1] / 4;
  const int B = in_sizes[0] / (CCH * HWW);

  const size_t need = (size_t)B * HWW * CCH * sizeof(unsigned short);
  if (ws_size >= need) {
    unsigned short* ft = (unsigned short*)d_ws;
    dim3 tgrid(HWW / 64, CCH / 64, B);
    transpose_kernel<<<tgrid, 256, 0, stream>>>(features, ft);
    roi_kernel<<<4 * N, 256, 0, stream>>>(ft, rois, sidx, out);
  } else {
    roi_kernel_nchw<<<N, 256, 0, stream>>>(features, rois, sidx, out);
  }
}